// Round 7
// baseline (135.718 us; speedup 1.0000x reference)
//
#include <hip/hip_runtime.h>
#include <hip/hip_fp16.h>

// ImportancePooling: N=100000, K=32, D=64.
// Staged-fp16 gather; the kernel is L2-miss-path bound (~132MB of random
// 128B-line misses). Streaming traffic (headers 25.6MB + out 25.6MB) was
// flushing the 4MiB/XCD L2 every ~10us, evicting reusable x lines.
// -> mark all streaming accesses non-temporal (nt bit) so only the gather
//    working set competes for L2 residency.
// NOTE: __builtin_nontemporal_* needs clang native vector types, not
// HIP_vector_type structs -> use ext_vector_type aliases.

#define K_NBR 32
#define D_FEAT 64

typedef float vfloat4 __attribute__((ext_vector_type(4)));
typedef unsigned int vuint2 __attribute__((ext_vector_type(2)));

__global__ __launch_bounds__(256) void ImportancePooling_28424093564958_convert(
    const vfloat4* __restrict__ x4, vuint2* __restrict__ xh4, int n4) {
  const int i = blockIdx.x * blockDim.x + threadIdx.x;
  if (i < n4) {
    const vfloat4 v = __builtin_nontemporal_load(x4 + i);  // x read once
    const __half2 a = __floats2half2_rn(v.x, v.y);
    const __half2 b = __floats2half2_rn(v.z, v.w);
    vuint2 u;
    u.x = *(const unsigned int*)&a;
    u.y = *(const unsigned int*)&b;
    xh4[i] = u;  // keep default: xh is re-read by the gather kernel
  }
}

__global__ __launch_bounds__(256) void ImportancePooling_28424093564958_kernel(
    const __half* __restrict__ xh,      // [N, 64] staged fp16
    const int* __restrict__ neighbors,  // [N, 32]
    const float* __restrict__ weights,  // [N, 32]
    float* __restrict__ out,            // [N, 64]
    int N) {
  const int wave_id = (int)((blockIdx.x * blockDim.x + threadIdx.x) >> 6);
  const int lane = threadIdx.x & 63;
  if (wave_id >= N) return;

  // Merged header (streamed once -> non-temporal):
  // lanes 0..31 carry weights (bits), lanes 32..63 carry neighbor ids.
  const long hbase = (long)wave_id * K_NBR;
  int packed;
  if (lane < K_NBR) {
    packed = __float_as_int(__builtin_nontemporal_load(weights + hbase + lane));
  } else {
    packed = __builtin_nontemporal_load(neighbors + hbase + (lane - K_NBR));
  }

  // K-loop: readlane -> SGPR-uniform (wk, idx); gather keeps default caching
  // (this is the reusable working set we want resident in L2).
  float acc = 0.0f;
  float wsum = 0.0f;
  #pragma unroll
  for (int k = 0; k < K_NBR; ++k) {
    const float wk = __int_as_float(__builtin_amdgcn_readlane(packed, k));
    const int idx = __builtin_amdgcn_readlane(packed, K_NBR + k);
    wsum += wk;
    acc = fmaf(wk, __half2float(xh[(long)idx * D_FEAT + lane]), acc);
  }

  const float inv = (wsum > 0.0f) ? (1.0f / wsum) : 1.0f;
  __builtin_nontemporal_store(acc * inv, out + (long)wave_id * D_FEAT + lane);
}

// Fallback (ws too small): direct fp32 gather, identical math.
__global__ __launch_bounds__(256) void ImportancePooling_28424093564958_f32(
    const float* __restrict__ x, const int* __restrict__ neighbors,
    const float* __restrict__ weights, float* __restrict__ out, int N) {
  const int wave_id = (int)((blockIdx.x * blockDim.x + threadIdx.x) >> 6);
  const int lane = threadIdx.x & 63;
  if (wave_id >= N) return;
  const long hbase = (long)wave_id * K_NBR;
  int packed;
  if (lane < K_NBR) {
    packed = __float_as_int(weights[hbase + lane]);
  } else {
    packed = neighbors[hbase + (lane - K_NBR)];
  }
  float acc = 0.0f, wsum = 0.0f;
  #pragma unroll
  for (int k = 0; k < K_NBR; ++k) {
    const float wk = __int_as_float(__builtin_amdgcn_readlane(packed, k));
    const int idx = __builtin_amdgcn_readlane(packed, K_NBR + k);
    wsum += wk;
    acc += wk * x[(long)idx * D_FEAT + lane];
  }
  const float inv = (wsum > 0.0f) ? (1.0f / wsum) : 1.0f;
  out[(long)wave_id * D_FEAT + lane] = acc * inv;
}

extern "C" void kernel_launch(void* const* d_in, const int* in_sizes, int n_in,
                              void* d_out, int out_size, void* d_ws, size_t ws_size,
                              hipStream_t stream) {
  const float* x = (const float*)d_in[0];
  const int* neighbors = (const int*)d_in[1];
  const float* weights = (const float*)d_in[2];
  float* out = (float*)d_out;

  const int N = in_sizes[0] / D_FEAT;  // 100000
  const int block = 256;               // 4 waves/block
  const int grid = (N * 64 + block - 1) / block;

  const size_t xh_bytes = (size_t)N * D_FEAT * sizeof(__half);
  if (ws_size >= xh_bytes) {
    __half* xh = (__half*)d_ws;
    const int n4 = N * D_FEAT / 4;
    ImportancePooling_28424093564958_convert<<<(n4 + 255) / 256, 256, 0, stream>>>(
        (const vfloat4*)x, (vuint2*)d_ws, n4);
    ImportancePooling_28424093564958_kernel<<<grid, block, 0, stream>>>(
        xh, neighbors, weights, out, N);
  } else {
    ImportancePooling_28424093564958_f32<<<grid, block, 0, stream>>>(
        x, neighbors, weights, out, N);
  }
}